// Round 1
// baseline (642.979 us; speedup 1.0000x reference)
//
#include <hip/hip_runtime.h>
#include <hip/hip_bf16.h>
#include <cfloat>

#define DIM 690
#define NF2 345   // DIM/2, exact
#define N_CLS 53

// ---------------------------------------------------------------------------
// K1: per-sentence attention logit: logit[i] = sum_d x[i,d]*att[q,d]*rel[q,d]
// One wave (64 lanes) per sentence; float2 vectorized loads (rows are 8B
// aligned: 690*4 = 2760 bytes, divisible by 8).
// ---------------------------------------------------------------------------
__global__ __launch_bounds__(256) void logit_kernel(
    const float* __restrict__ x,
    const float* __restrict__ rel_w,
    const float* __restrict__ att_w,
    const int* __restrict__ query,
    float* __restrict__ logit,
    int n_sent)
{
    int wave = (int)((blockIdx.x * blockDim.x + threadIdx.x) >> 6);
    int lane = threadIdx.x & 63;
    if (wave >= n_sent) return;

    int q = query[wave];
    const float2* xr = reinterpret_cast<const float2*>(x + (size_t)wave * DIM);
    const float2* ar = reinterpret_cast<const float2*>(att_w + (size_t)q * DIM);
    const float2* rr = reinterpret_cast<const float2*>(rel_w + (size_t)q * DIM);

    float acc = 0.f;
    #pragma unroll
    for (int k = 0; k < 6; ++k) {
        int idx = lane + k * 64;
        if (idx < NF2) {
            float2 xv = xr[idx];
            float2 av = ar[idx];
            float2 rv = rr[idx];
            acc += xv.x * av.x * rv.x + xv.y * av.y * rv.y;
        }
    }
    // wave-wide sum reduce (64 lanes)
    #pragma unroll
    for (int off = 32; off > 0; off >>= 1)
        acc += __shfl_down(acc, off);
    if (lane == 0) logit[wave] = acc;
}

// ---------------------------------------------------------------------------
// K2: per-bag softmax stats: m[b] = max logit, denom[b] = sum exp(logit - m).
// One wave per bag.
// ---------------------------------------------------------------------------
__global__ __launch_bounds__(256) void stats_kernel(
    const float* __restrict__ logit,
    const int* __restrict__ scope,
    float* __restrict__ m_out,
    float* __restrict__ denom_out,
    int n_bags)
{
    int wave = (int)((blockIdx.x * blockDim.x + threadIdx.x) >> 6);
    int lane = threadIdx.x & 63;
    if (wave >= n_bags) return;

    int s = scope[wave];
    int e = scope[wave + 1];

    float m = -FLT_MAX;
    for (int i = s + lane; i < e; i += 64)
        m = fmaxf(m, logit[i]);
    #pragma unroll
    for (int off = 32; off > 0; off >>= 1)
        m = fmaxf(m, __shfl_xor(m, off));

    float sum = 0.f;
    for (int i = s + lane; i < e; i += 64)
        sum += __expf(logit[i] - m);
    #pragma unroll
    for (int off = 32; off > 0; off >>= 1)
        sum += __shfl_xor(sum, off);

    if (lane == 0) {
        m_out[wave] = m;
        denom_out[wave] = sum;
    }
}

// ---------------------------------------------------------------------------
// K3: one block (256 threads) per bag.
//  Phase 1: repr[d] = sum_{i in bag} w_i * x[i,d], accumulated in registers
//           (each thread owns dims t, t+256, t+512), written to LDS.
//  Phase 2: out[b,c] = repr . rel_w[c] + bias[c]; 4 waves split the 53
//           classes, lanes stride the 690 dims, shuffle reduce.
// ---------------------------------------------------------------------------
__global__ __launch_bounds__(256) void bag_kernel(
    const float* __restrict__ x,
    const float* __restrict__ rel_w,
    const float* __restrict__ bias,
    const int* __restrict__ scope,
    const float* __restrict__ logit,
    const float* __restrict__ m_arr,
    const float* __restrict__ denom_arr,
    float* __restrict__ out)
{
    int b = blockIdx.x;
    int t = threadIdx.x;

    __shared__ float repr[DIM];

    int s = scope[b];
    int e = scope[b + 1];
    float m = m_arr[b];
    float inv_denom = 1.f / denom_arr[b];

    float r0 = 0.f, r1 = 0.f, r2 = 0.f;
    const bool has2 = (t + 512) < DIM;   // t < 178

    for (int i = s; i < e; ++i) {
        float w = __expf(logit[i] - m) * inv_denom;
        const float* xr = x + (size_t)i * DIM;
        r0 += w * xr[t];
        r1 += w * xr[t + 256];          // t+256 <= 511 < 690 always
        if (has2) r2 += w * xr[t + 512];
    }
    repr[t] = r0;
    repr[t + 256] = r1;
    if (has2) repr[t + 512] = r2;
    __syncthreads();

    int wid = t >> 6;
    int lane = t & 63;
    for (int c = wid; c < N_CLS; c += 4) {
        const float* rw = rel_w + (size_t)c * DIM;
        float acc = 0.f;
        for (int d = lane; d < DIM; d += 64)
            acc += repr[d] * rw[d];
        #pragma unroll
        for (int off = 32; off > 0; off >>= 1)
            acc += __shfl_down(acc, off);
        if (lane == 0)
            out[(size_t)b * N_CLS + c] = acc + bias[c];
    }
}

// ---------------------------------------------------------------------------
extern "C" void kernel_launch(void* const* d_in, const int* in_sizes, int n_in,
                              void* d_out, int out_size, void* d_ws, size_t ws_size,
                              hipStream_t stream)
{
    const float* x       = (const float*)d_in[0];
    const float* rel_w   = (const float*)d_in[1];
    const float* att_w   = (const float*)d_in[2];
    const float* bias    = (const float*)d_in[3];
    const int*   query   = (const int*)d_in[4];
    const int*   scope   = (const int*)d_in[5];
    float*       out     = (float*)d_out;

    const int n_sent = in_sizes[0] / DIM;
    const int n_bags = in_sizes[5] - 1;

    float* logit = (float*)d_ws;
    float* m_buf = logit + n_sent;
    float* d_buf = m_buf + n_bags;

    // K1: one wave per sentence, 4 waves per block
    {
        int waves = n_sent;
        int blocks = (waves + 3) / 4;
        logit_kernel<<<blocks, 256, 0, stream>>>(x, rel_w, att_w, query, logit, n_sent);
    }
    // K2: one wave per bag
    {
        int blocks = (n_bags + 3) / 4;
        stats_kernel<<<blocks, 256, 0, stream>>>(logit, scope, m_buf, d_buf, n_bags);
    }
    // K3: one block per bag
    {
        bag_kernel<<<n_bags, 256, 0, stream>>>(x, rel_w, bias, scope, logit,
                                               m_buf, d_buf, out);
    }
}

// Round 2
// 451.851 us; speedup vs baseline: 1.4230x; 1.4230x over previous
//
#include <hip/hip_runtime.h>
#include <hip/hip_bf16.h>
#include <cfloat>

#define DIM 690
#define KPAD 704          // 22 chunks of 32
#define NCHUNK 22
#define N_CLS 53
#define YLD 56            // y leading dim (53 cols padded)

typedef short bf16x8 __attribute__((ext_vector_type(8)));
typedef float f32x4  __attribute__((ext_vector_type(4)));

static __device__ __forceinline__ float bf2f(unsigned short u) {
    union { unsigned int i; float f; } v; v.i = ((unsigned int)u) << 16; return v.f;
}
static __device__ __forceinline__ short f2bf(float f) {
    __hip_bfloat16 h = __float2bfloat16(f);
    return *reinterpret_cast<short*>(&h);
}

// ---------------------------------------------------------------------------
// P0: pack W_b[64][704] = bf16(rel_w) zero-padded, and aw_b[64][704] =
// bf16(att*rel) zero-padded (product taken in fp32).
// ---------------------------------------------------------------------------
__global__ __launch_bounds__(256) void prep_kernel(
    const float* __restrict__ rel_w, const float* __restrict__ att_w,
    unsigned short* __restrict__ wb, unsigned short* __restrict__ awb)
{
    int idx = blockIdx.x * blockDim.x + threadIdx.x;
    const int half = 64 * KPAD;
    if (idx >= 2 * half) return;
    int which = idx >= half;
    int j = which ? idx - half : idx;
    int r = j / KPAD, k = j % KPAD;
    float v = 0.f;
    if (r < N_CLS && k < DIM) {
        float rv = rel_w[r * DIM + k];
        v = which ? att_w[r * DIM + k] * rv : rv;
    }
    (which ? awb : wb)[j] = (unsigned short)f2bf(v);
}

// ---------------------------------------------------------------------------
// K1: fused score GEMM. Block = 256 thr (4 waves), each wave owns 16 rows.
// Per 32-k chunk: A-frag from x (fp32->bf16, direct from global), 4 B-frags
// from W_b (cols 0..63), 4 x mfma_f32_16x16x32_bf16 -> y[row][0..52].
// Simultaneously: logit partial = sum a[j] * aw[q_row][k] on VALU.
// A layout: row = lane&15, k = 8*(lane>>4)+j.  B: col = lane&15, same k.
// D: col = lane&15, row = (lane>>4)*4 + reg   [guide m89/m91 verified].
// ---------------------------------------------------------------------------
__global__ __launch_bounds__(256) void score_kernel(
    const float* __restrict__ x,
    const unsigned short* __restrict__ wb,
    const unsigned short* __restrict__ awb,
    const int* __restrict__ query,
    unsigned short* __restrict__ y,
    float* __restrict__ logit)
{
    const int wave = threadIdx.x >> 6;
    const int lane = threadIdx.x & 63;
    const int r  = lane & 15;
    const int kg = lane >> 4;
    const int rowBase = blockIdx.x * 64 + wave * 16;
    const int grow = rowBase + r;              // this lane's A-row
    const int q = query[grow];

    const float* xrow = x + (size_t)grow * DIM;
    const unsigned short* awrow = awb + (size_t)q * KPAD;
    const unsigned short* w0 = wb + (size_t)(0 * 16 + r) * KPAD;
    const unsigned short* w1 = wb + (size_t)(1 * 16 + r) * KPAD;
    const unsigned short* w2 = wb + (size_t)(2 * 16 + r) * KPAD;
    const unsigned short* w3 = wb + (size_t)(3 * 16 + r) * KPAD;

    f32x4 acc0 = {0.f,0.f,0.f,0.f};
    f32x4 acc1 = {0.f,0.f,0.f,0.f};
    f32x4 acc2 = {0.f,0.f,0.f,0.f};
    f32x4 acc3 = {0.f,0.f,0.f,0.f};
    float lg = 0.f;

    for (int kk = 0; kk < NCHUNK; ++kk) {
        const int k0 = kk * 32 + kg * 8;      // this lane's 8-elem k-slice
        float a[8];
        if (kk < NCHUNK - 1) {
            // rows are only 8B-aligned (2760 B stride) -> float2 loads
            const float2* p = reinterpret_cast<const float2*>(xrow + k0);
            float2 v0 = p[0], v1 = p[1], v2 = p[2], v3 = p[3];
            a[0]=v0.x; a[1]=v0.y; a[2]=v1.x; a[3]=v1.y;
            a[4]=v2.x; a[5]=v2.y; a[6]=v3.x; a[7]=v3.y;
        } else {
            #pragma unroll
            for (int j = 0; j < 8; ++j) {
                int k = k0 + j;
                a[j] = (k < DIM) ? xrow[k] : 0.f;
            }
        }
        bf16x8 af;
        #pragma unroll
        for (int j = 0; j < 8; ++j) af[j] = f2bf(a[j]);

        // attention-logit partial (aw_b is zero-padded past k=689)
        bf16x8 awf = *reinterpret_cast<const bf16x8*>(awrow + k0);
        #pragma unroll
        for (int j = 0; j < 8; ++j)
            lg += a[j] * bf2f((unsigned short)awf[j]);

        bf16x8 b0 = *reinterpret_cast<const bf16x8*>(w0 + k0);
        bf16x8 b1 = *reinterpret_cast<const bf16x8*>(w1 + k0);
        bf16x8 b2 = *reinterpret_cast<const bf16x8*>(w2 + k0);
        bf16x8 b3 = *reinterpret_cast<const bf16x8*>(w3 + k0);
        acc0 = __builtin_amdgcn_mfma_f32_16x16x32_bf16(af, b0, acc0, 0, 0, 0);
        acc1 = __builtin_amdgcn_mfma_f32_16x16x32_bf16(af, b1, acc1, 0, 0, 0);
        acc2 = __builtin_amdgcn_mfma_f32_16x16x32_bf16(af, b2, acc2, 0, 0, 0);
        acc3 = __builtin_amdgcn_mfma_f32_16x16x32_bf16(af, b3, acc3, 0, 0, 0);
    }

    // reduce logit partials across the 4 k-groups (lanes r, r+16, r+32, r+48)
    lg += __shfl_xor(lg, 16);
    lg += __shfl_xor(lg, 32);
    if (lane < 16) logit[rowBase + lane] = lg;

    // epilogue: D col = lane&15, row = kg*4 + reg
    #pragma unroll
    for (int reg = 0; reg < 4; ++reg) {
        int grow2 = rowBase + kg * 4 + reg;
        size_t base = (size_t)grow2 * YLD;
        int c0 = 0 * 16 + r, c1 = 1 * 16 + r, c2 = 2 * 16 + r, c3 = 3 * 16 + r;
        y[base + c0] = (unsigned short)f2bf(acc0[reg]);
        y[base + c1] = (unsigned short)f2bf(acc1[reg]);
        y[base + c2] = (unsigned short)f2bf(acc2[reg]);
        if (c3 < YLD) y[base + c3] = (unsigned short)f2bf(acc3[reg]);
    }
}

// ---------------------------------------------------------------------------
// K2: per-bag softmax -> per-sentence weight w[i]. One wave per bag.
// ---------------------------------------------------------------------------
__global__ __launch_bounds__(256) void weight_kernel(
    const float* __restrict__ logit,
    const int* __restrict__ scope,
    float* __restrict__ w_buf,
    int n_bags)
{
    int bag  = (int)((blockIdx.x * blockDim.x + threadIdx.x) >> 6);
    int lane = threadIdx.x & 63;
    if (bag >= n_bags) return;
    int s = scope[bag], e = scope[bag + 1];

    float m = -FLT_MAX;
    for (int i = s + lane; i < e; i += 64) m = fmaxf(m, logit[i]);
    #pragma unroll
    for (int off = 32; off > 0; off >>= 1) m = fmaxf(m, __shfl_xor(m, off));

    float sum = 0.f;
    for (int i = s + lane; i < e; i += 64) sum += __expf(logit[i] - m);
    #pragma unroll
    for (int off = 32; off > 0; off >>= 1) sum += __shfl_xor(sum, off);

    float inv = 1.f / sum;
    for (int i = s + lane; i < e; i += 64)
        w_buf[i] = __expf(logit[i] - m) * inv;
}

// ---------------------------------------------------------------------------
// K3: out[b,c] = sum_i w[i] * y[i,c] + bias[c]. One wave per bag, lane = col.
// ---------------------------------------------------------------------------
__global__ __launch_bounds__(256) void out_kernel(
    const unsigned short* __restrict__ y,
    const float* __restrict__ w_buf,
    const float* __restrict__ bias,
    const int* __restrict__ scope,
    float* __restrict__ out,
    int n_bags)
{
    int bag  = (int)((blockIdx.x * blockDim.x + threadIdx.x) >> 6);
    int lane = threadIdx.x & 63;
    if (bag >= n_bags) return;
    int s = scope[bag], e = scope[bag + 1];

    float acc = 0.f;
    if (lane < YLD) {
        for (int i = s; i < e; ++i)
            acc += w_buf[i] * bf2f(y[(size_t)i * YLD + lane]);
    }
    if (lane < N_CLS) out[(size_t)bag * N_CLS + lane] = acc + bias[lane];
}

// ---------------------------------------------------------------------------
extern "C" void kernel_launch(void* const* d_in, const int* in_sizes, int n_in,
                              void* d_out, int out_size, void* d_ws, size_t ws_size,
                              hipStream_t stream)
{
    const float* x     = (const float*)d_in[0];
    const float* rel_w = (const float*)d_in[1];
    const float* att_w = (const float*)d_in[2];
    const float* bias  = (const float*)d_in[3];
    const int*   query = (const int*)d_in[4];
    const int*   scope = (const int*)d_in[5];
    float*       out   = (float*)d_out;

    const int n_sent = in_sizes[0] / DIM;      // 262144
    const int n_bags = in_sizes[5] - 1;        // 8192

    // workspace layout
    unsigned short* wb    = (unsigned short*)d_ws;             // 64*704
    unsigned short* awb   = wb + 64 * KPAD;                    // 64*704
    float*          logit = (float*)(awb + 64 * KPAD);         // n_sent
    float*          w_buf = logit + n_sent;                    // n_sent
    unsigned short* y     = (unsigned short*)(w_buf + n_sent); // n_sent*YLD

    // P0: pack weights
    prep_kernel<<<(2 * 64 * KPAD + 255) / 256, 256, 0, stream>>>(rel_w, att_w, wb, awb);

    // K1: fused score GEMM + attention logit (one pass over x)
    score_kernel<<<n_sent / 64, 256, 0, stream>>>(x, wb, awb, query, y, logit);

    // K2: softmax weights
    weight_kernel<<<(n_bags * 64 + 255) / 256, 256, 0, stream>>>(logit, scope, w_buf, n_bags);

    // K3: weighted bag sum + bias
    out_kernel<<<(n_bags * 64 + 255) / 256, 256, 0, stream>>>(y, w_buf, bias, scope, out, n_bags);
}

// Round 3
// 314.179 us; speedup vs baseline: 2.0465x; 1.4382x over previous
//
#include <hip/hip_runtime.h>
#include <hip/hip_bf16.h>
#include <cfloat>

#define DIM 690
#define KPAD 704          // 22 chunks of 32
#define NCHUNK 22
#define N_CLS 53
#define YLD 56            // y leading dim (53 cols padded)
#define BM 32             // rows per block
#define LDS_LD 720        // LDS row stride in shorts (1440 B: 16B-aligned, bank-uniform)

typedef short bf16x8 __attribute__((ext_vector_type(8)));
typedef float f32x4  __attribute__((ext_vector_type(4)));

static __device__ __forceinline__ float bf2f(unsigned short u) {
    union { unsigned int i; float f; } v; v.i = ((unsigned int)u) << 16; return v.f;
}
static __device__ __forceinline__ unsigned short f2bf(float f) {
    __hip_bfloat16 h = __float2bfloat16(f);
    return *reinterpret_cast<unsigned short*>(&h);
}

// ---------------------------------------------------------------------------
// P0: pack
//  wbp  — fragment-ordered B: wbp[((kk*4+kg)*64 + c)*8 + j] = bf16(rel_w[c][k])
//         with k = kk*32+kg*8+j, zero-padded (c>=53 or k>=690)
//  awb  — row-major bf16(att*rel) [64][704], zero-padded (gathered by query)
// ---------------------------------------------------------------------------
__global__ __launch_bounds__(256) void prep_kernel(
    const float* __restrict__ rel_w, const float* __restrict__ att_w,
    unsigned short* __restrict__ wbp, unsigned short* __restrict__ awb)
{
    int idx = blockIdx.x * blockDim.x + threadIdx.x;
    const int NW = NCHUNK * 4 * 512;   // 45056
    const int NA = 64 * KPAD;          // 45056
    if (idx < NW) {
        int kkg = idx >> 9;            // kk*4+kg
        int rem = idx & 511;
        int c = rem >> 3, j = rem & 7;
        int k = (kkg >> 2) * 32 + (kkg & 3) * 8 + j;
        float v = (c < N_CLS && k < DIM) ? rel_w[c * DIM + k] : 0.f;
        wbp[idx] = f2bf(v);
    } else if (idx < NW + NA) {
        int i2 = idx - NW;
        int rr = i2 / KPAD, k = i2 - rr * KPAD;
        float v = 0.f;
        if (rr < N_CLS && k < DIM) v = att_w[rr * DIM + k] * rel_w[rr * DIM + k];
        awb[i2] = f2bf(v);
    }
}

// ---------------------------------------------------------------------------
// K1: fused score GEMM + attention logit, one coalesced pass over x.
// Block = 256 thr (4 waves), BM=32 rows. Stage x slab (fp32->bf16) into LDS
// coalesced; then 22 k-chunks of mfma_f32_16x16x32_bf16.
// Wave w: rowgroup rg=w>>1 (16 rows), colpair cp=w&1 (cols 32cp..32cp+31).
// Even waves (cp==0) also accumulate the attention logit from the same
// A-fragments vs awb[q] (gather).
// A/B frag: k = 8*(lane>>4)+j ; A row / B col = lane&15.
// D frag: col = lane&15, row = (lane>>4)*4 + reg  [verified R2: absmax ok].
// ---------------------------------------------------------------------------
__global__ __launch_bounds__(256) void score_kernel(
    const float* __restrict__ x,
    const unsigned short* __restrict__ wbp,
    const unsigned short* __restrict__ awb,
    const int* __restrict__ query,
    unsigned short* __restrict__ y,
    float* __restrict__ logit)
{
    __shared__ unsigned short xs[BM][LDS_LD];

    const int t = threadIdx.x;
    const int rowBase = blockIdx.x * BM;

    // ---- stage: 8 threads per row, float2 loads (rows are 8B-aligned) ----
    {
        const int srow = t >> 3, sub = t & 7;
        // zero the pad region cols 688..719 (cols 688/689 re-written below)
        *reinterpret_cast<uint2*>(&xs[srow][688 + sub * 4]) = make_uint2(0u, 0u);
        const float* xrow = x + (size_t)(rowBase + srow) * DIM;
        #pragma unroll
        for (int s = 0; s < 44; ++s) {
            int col = s * 16 + sub * 2;
            if (col < DIM) {
                float2 v = *reinterpret_cast<const float2*>(xrow + col);
                unsigned int p = (unsigned int)f2bf(v.x) | ((unsigned int)f2bf(v.y) << 16);
                *reinterpret_cast<unsigned int*>(&xs[srow][col]) = p;
            }
        }
    }
    __syncthreads();

    const int lane = t & 63;
    const int wv = t >> 6;
    const int rg = wv >> 1, cp = wv & 1;
    const int r = lane & 15, kg = lane >> 4;
    const int lrow = rg * 16 + r;

    f32x4 acc0 = {0.f, 0.f, 0.f, 0.f};
    f32x4 acc1 = {0.f, 0.f, 0.f, 0.f};
    float lg = 0.f;
    const unsigned short* awrow = nullptr;
    if (cp == 0)
        awrow = awb + (size_t)query[rowBase + lrow] * KPAD;

    for (int kk = 0; kk < NCHUNK; ++kk) {
        bf16x8 af = *reinterpret_cast<const bf16x8*>(&xs[lrow][kk * 32 + kg * 8]);
        const unsigned short* bp = wbp + (size_t)((kk * 4 + kg) * 512 + (cp * 32 + r) * 8);
        bf16x8 b0 = *reinterpret_cast<const bf16x8*>(bp);
        bf16x8 b1 = *reinterpret_cast<const bf16x8*>(bp + 128);  // +16 cols
        if (cp == 0) {
            bf16x8 awf = *reinterpret_cast<const bf16x8*>(awrow + kk * 32 + kg * 8);
            #pragma unroll
            for (int j = 0; j < 8; ++j)
                lg += bf2f((unsigned short)af[j]) * bf2f((unsigned short)awf[j]);
        }
        acc0 = __builtin_amdgcn_mfma_f32_16x16x32_bf16(af, b0, acc0, 0, 0, 0);
        acc1 = __builtin_amdgcn_mfma_f32_16x16x32_bf16(af, b1, acc1, 0, 0, 0);
    }

    // logit: reduce partials across the 4 k-groups, lanes 0..15 hold rows
    if (cp == 0) {
        lg += __shfl_xor(lg, 16);
        lg += __shfl_xor(lg, 32);
        if (lane < 16)
            logit[rowBase + rg * 16 + lane] = lg;
    }

    // epilogue: D col = lane&15 (within colgroup), row = kg*4 + reg
    #pragma unroll
    for (int reg = 0; reg < 4; ++reg) {
        int grow = rowBase + rg * 16 + kg * 4 + reg;
        size_t base = (size_t)grow * YLD;
        int c0 = cp * 32 + r;
        int c1 = c0 + 16;
        y[base + c0] = f2bf(acc0[reg]);
        if (c1 < YLD) y[base + c1] = f2bf(acc1[reg]);
    }
}

// ---------------------------------------------------------------------------
// K2: per-bag softmax -> per-sentence weight w[i]. One wave per bag.
// ---------------------------------------------------------------------------
__global__ __launch_bounds__(256) void weight_kernel(
    const float* __restrict__ logit,
    const int* __restrict__ scope,
    float* __restrict__ w_buf,
    int n_bags)
{
    int bag  = (int)((blockIdx.x * blockDim.x + threadIdx.x) >> 6);
    int lane = threadIdx.x & 63;
    if (bag >= n_bags) return;
    int s = scope[bag], e = scope[bag + 1];

    float m = -FLT_MAX;
    for (int i = s + lane; i < e; i += 64) m = fmaxf(m, logit[i]);
    #pragma unroll
    for (int off = 32; off > 0; off >>= 1) m = fmaxf(m, __shfl_xor(m, off));

    float sum = 0.f;
    for (int i = s + lane; i < e; i += 64) sum += __expf(logit[i] - m);
    #pragma unroll
    for (int off = 32; off > 0; off >>= 1) sum += __shfl_xor(sum, off);

    float inv = 1.f / sum;
    for (int i = s + lane; i < e; i += 64)
        w_buf[i] = __expf(logit[i] - m) * inv;
}

// ---------------------------------------------------------------------------
// K3: out[b,c] = sum_i w[i] * y[i,c] + bias[c]. One wave per bag, lane = col.
// (y cols 53..55 are exact zeros — padded W columns.)
// ---------------------------------------------------------------------------
__global__ __launch_bounds__(256) void out_kernel(
    const unsigned short* __restrict__ y,
    const float* __restrict__ w_buf,
    const float* __restrict__ bias,
    const int* __restrict__ scope,
    float* __restrict__ out,
    int n_bags)
{
    int bag  = (int)((blockIdx.x * blockDim.x + threadIdx.x) >> 6);
    int lane = threadIdx.x & 63;
    if (bag >= n_bags) return;
    int s = scope[bag], e = scope[bag + 1];

    float acc = 0.f;
    if (lane < YLD) {
        for (int i = s; i < e; ++i)
            acc += w_buf[i] * bf2f(y[(size_t)i * YLD + lane]);
    }
    if (lane < N_CLS) out[(size_t)bag * N_CLS + lane] = acc + bias[lane];
}

// ---------------------------------------------------------------------------
extern "C" void kernel_launch(void* const* d_in, const int* in_sizes, int n_in,
                              void* d_out, int out_size, void* d_ws, size_t ws_size,
                              hipStream_t stream)
{
    const float* x     = (const float*)d_in[0];
    const float* rel_w = (const float*)d_in[1];
    const float* att_w = (const float*)d_in[2];
    const float* bias  = (const float*)d_in[3];
    const int*   query = (const int*)d_in[4];
    const int*   scope = (const int*)d_in[5];
    float*       out   = (float*)d_out;

    const int n_sent = in_sizes[0] / DIM;      // 262144
    const int n_bags = in_sizes[5] - 1;        // 8192

    // workspace layout
    unsigned short* wbp   = (unsigned short*)d_ws;             // 45056
    unsigned short* awb   = wbp + NCHUNK * 4 * 512;            // 45056
    float*          logit = (float*)(awb + 64 * KPAD);         // n_sent
    float*          w_buf = logit + n_sent;                    // n_sent
    unsigned short* y     = (unsigned short*)(w_buf + n_sent); // n_sent*YLD

    // P0: pack weights
    prep_kernel<<<(NCHUNK * 4 * 512 + 64 * KPAD + 255) / 256, 256, 0, stream>>>(
        rel_w, att_w, wbp, awb);

    // K1: fused score GEMM + attention logit (one coalesced pass over x)
    score_kernel<<<n_sent / BM, 256, 0, stream>>>(x, wbp, awb, query, y, logit);

    // K2: softmax weights
    weight_kernel<<<(n_bags * 64 + 255) / 256, 256, 0, stream>>>(logit, scope, w_buf, n_bags);

    // K3: weighted bag sum + bias
    out_kernel<<<(n_bags * 64 + 255) / 256, 256, 0, stream>>>(y, w_buf, bias, scope, out, n_bags);
}

// Round 4
// 233.045 us; speedup vs baseline: 2.7590x; 1.3481x over previous
//
#include <hip/hip_runtime.h>
#include <hip/hip_bf16.h>
#include <cfloat>

#define DIM 690
#define KPAD 704          // 22 chunks of 32
#define NCHUNK 22
#define N_CLS 53
#define YLD 64            // y row stride in shorts (128 B rows)
#define BM 16             // rows per slab
#define LDS_LD 720        // LDS row stride in shorts (1440 B)
#define GRID_SCORE 768    // 3 blocks/CU x 256 CU
#define NSLAB 16384       // 262144 / BM

typedef short bf16x8 __attribute__((ext_vector_type(8)));
typedef float f32x4  __attribute__((ext_vector_type(4)));

static __device__ __forceinline__ float bf2f(unsigned short u) {
    union { unsigned int i; float f; } v; v.i = ((unsigned int)u) << 16; return v.f;
}
static __device__ __forceinline__ unsigned short f2bf(float f) {
    __hip_bfloat16 h = __float2bfloat16(f);
    return *reinterpret_cast<unsigned short*>(&h);
}

// ---------------------------------------------------------------------------
// P0: pack
//  wbp — fragment-ordered B: wbp[((kk*4+kg)*64 + c)*8 + j] = bf16(rel_w[c][k]),
//        k = kk*32 + kg*8 + j, zero-padded (c>=53 or k>=690)
//  awb — row-major bf16(att*rel) [64][704], zero-padded
// ---------------------------------------------------------------------------
__global__ __launch_bounds__(256) void prep_kernel(
    const float* __restrict__ rel_w, const float* __restrict__ att_w,
    unsigned short* __restrict__ wbp, unsigned short* __restrict__ awb)
{
    int idx = blockIdx.x * blockDim.x + threadIdx.x;
    const int NW = NCHUNK * 4 * 512;   // 45056
    const int NA = 64 * KPAD;          // 45056
    if (idx < NW) {
        int kkg = idx >> 9;            // kk*4+kg
        int rem = idx & 511;
        int c = rem >> 3, j = rem & 7;
        int k = (kkg >> 2) * 32 + (kkg & 3) * 8 + j;
        float v = (c < N_CLS && k < DIM) ? rel_w[c * DIM + k] : 0.f;
        wbp[idx] = f2bf(v);
    } else if (idx < NW + NA) {
        int i2 = idx - NW;
        int rr = i2 / KPAD, k = i2 - rr * KPAD;
        float v = 0.f;
        if (rr < N_CLS && k < DIM) v = att_w[rr * DIM + k] * rel_w[rr * DIM + k];
        awb[i2] = f2bf(v);
    }
}

// ---------------------------------------------------------------------------
// K1: fused score GEMM + attention logit. Persistent blocks, BM=16 slabs,
// double-buffered LDS, T14 async-stage split (load regs early, write late).
// 4 waves; wave w computes cols 16w..16w+15 (1 MFMA per 32-k chunk) and the
// logit partial for k-chunks [6w, 6w+6) (wave-uniform branch); cross-wave
// logit reduce via small LDS array.
// A/B frag: k = 8*(lane>>4)+j, A row / B col = lane&15.
// D frag: col = lane&15, row = (lane>>4)*4 + reg.
// ---------------------------------------------------------------------------
__global__ __launch_bounds__(256) void score_kernel(
    const float* __restrict__ x,
    const unsigned short* __restrict__ wbp,
    const unsigned short* __restrict__ awb,
    const int* __restrict__ query,
    unsigned short* __restrict__ y,
    float* __restrict__ logit)
{
    __shared__ unsigned short xs[2][BM][LDS_LD];
    __shared__ float lgp[4][16];

    const int t = threadIdx.x;
    const int lane = t & 63;
    const int wv = t >> 6;
    const int r = lane & 15, kg = lane >> 4;
    const int srow = t >> 4, sub = t & 15;   // stage: 16 threads per row

    float2 sreg[NCHUNK];

    int slab = blockIdx.x;

    // ---- prologue: load + write slab0 into buf 0 ----
    {
        const float* xrow = x + ((size_t)slab * BM + srow) * DIM;
        #pragma unroll
        for (int s = 0; s < NCHUNK; ++s) {
            int col = s * 32 + sub * 2;
            sreg[s] = (col <= 688) ? *reinterpret_cast<const float2*>(xrow + col)
                                   : make_float2(0.f, 0.f);
        }
        #pragma unroll
        for (int s = 0; s < NCHUNK; ++s) {
            int col = s * 32 + sub * 2;
            unsigned int p = (unsigned int)f2bf(sreg[s].x)
                           | ((unsigned int)f2bf(sreg[s].y) << 16);
            *reinterpret_cast<unsigned int*>(&xs[0][srow][col]) = p;
        }
    }
    __syncthreads();

    int buf = 0;
    const int lo = wv * 6;
    const int hi = (lo + 6 < NCHUNK) ? lo + 6 : NCHUNK;

    while (true) {
        const int next = slab + GRID_SCORE;
        const bool has_next = next < NSLAB;

        // ---- T14: issue next slab's global loads early ----
        if (has_next) {
            const float* xrow = x + ((size_t)next * BM + srow) * DIM;
            #pragma unroll
            for (int s = 0; s < NCHUNK; ++s) {
                int col = s * 32 + sub * 2;
                sreg[s] = (col <= 688) ? *reinterpret_cast<const float2*>(xrow + col)
                                       : make_float2(0.f, 0.f);
            }
        }

        // ---- compute current slab ----
        {
            const int rowBase = slab * BM;
            const unsigned short* awrow = awb + (size_t)query[rowBase + r] * KPAD;
            f32x4 acc = {0.f, 0.f, 0.f, 0.f};
            float lg = 0.f;
            #pragma unroll
            for (int kk = 0; kk < NCHUNK; ++kk) {
                bf16x8 af = *reinterpret_cast<const bf16x8*>(&xs[buf][r][kk * 32 + kg * 8]);
                bf16x8 bw = *reinterpret_cast<const bf16x8*>(
                    wbp + (size_t)(((kk * 4 + kg) * 64 + wv * 16 + r) * 8));
                if (kk >= lo && kk < hi) {   // wave-uniform
                    bf16x8 awf = *reinterpret_cast<const bf16x8*>(awrow + kk * 32 + kg * 8);
                    #pragma unroll
                    for (int j = 0; j < 8; ++j)
                        lg += bf2f((unsigned short)af[j]) * bf2f((unsigned short)awf[j]);
                }
                acc = __builtin_amdgcn_mfma_f32_16x16x32_bf16(af, bw, acc, 0, 0, 0);
            }
            // intra-wave logit reduce over the 4 k-groups
            lg += __shfl_xor(lg, 16);
            lg += __shfl_xor(lg, 32);
            if (lane < 16) lgp[wv][lane] = lg;

            // epilogue: y[row][col], col = wv*16 + r, row = kg*4 + reg
            #pragma unroll
            for (int reg = 0; reg < 4; ++reg) {
                int grow = rowBase + kg * 4 + reg;
                y[(size_t)grow * YLD + wv * 16 + r] = f2bf(acc[reg]);
            }
        }
        __syncthreads();   // lgp ready; xs[buf] free; safe to fill xs[buf^1]

        // ---- write-late: next slab into other buffer ----
        if (has_next) {
            #pragma unroll
            for (int s = 0; s < NCHUNK; ++s) {
                int col = s * 32 + sub * 2;
                unsigned int p = (unsigned int)f2bf(sreg[s].x)
                               | ((unsigned int)f2bf(sreg[s].y) << 16);
                *reinterpret_cast<unsigned int*>(&xs[buf ^ 1][srow][col]) = p;
            }
        }
        // cross-wave logit finalize
        if (t < 16)
            logit[slab * BM + t] = lgp[0][t] + lgp[1][t] + lgp[2][t] + lgp[3][t];

        if (!has_next) break;
        __syncthreads();
        buf ^= 1;
        slab = next;
    }
}

// ---------------------------------------------------------------------------
// K2: fused per-bag softmax + weighted sum + bias. One wave per bag.
// y rows are 128 B; lanes read u32 (2 cols): lane = (rowparity<<5) | colpair.
// Per instruction: 2 adjacent rows x 128 B = 256 B contiguous.
// ---------------------------------------------------------------------------
__global__ __launch_bounds__(256) void bag_kernel(
    const unsigned short* __restrict__ y,
    const float* __restrict__ logit,
    const float* __restrict__ bias,
    const int* __restrict__ scope,
    float* __restrict__ out,
    int n_bags)
{
    int bag  = (int)((blockIdx.x * blockDim.x + threadIdx.x) >> 6);
    int lane = threadIdx.x & 63;
    if (bag >= n_bags) return;
    int s = scope[bag], e = scope[bag + 1];

    float m = -FLT_MAX;
    for (int i = s + lane; i < e; i += 64) m = fmaxf(m, logit[i]);
    #pragma unroll
    for (int off = 32; off > 0; off >>= 1) m = fmaxf(m, __shfl_xor(m, off));

    float sum = 0.f;
    for (int i = s + lane; i < e; i += 64) sum += __expf(logit[i] - m);
    #pragma unroll
    for (int off = 32; off > 0; off >>= 1) sum += __shfl_xor(sum, off);
    float inv = 1.f / sum;

    const int cp = lane & 31;          // colpair: cols 2cp, 2cp+1
    const int rpar = lane >> 5;        // row parity
    const unsigned int* yu = reinterpret_cast<const unsigned int*>(y);

    float a0 = 0.f, a1 = 0.f;
    for (int base = s; base < e; base += 2) {
        int row = base + rpar;
        if (row < e) {
            float w = __expf(logit[row] - m) * inv;
            unsigned int v = yu[(size_t)row * (YLD / 2) + cp];
            union { unsigned int i; float f; } lo, hi;
            lo.i = v << 16;
            hi.i = v & 0xFFFF0000u;
            a0 += w * lo.f;
            a1 += w * hi.f;
        }
    }
    a0 += __shfl_xor(a0, 32);
    a1 += __shfl_xor(a1, 32);
    if (lane < 32) {
        int c0 = 2 * lane, c1 = 2 * lane + 1;
        if (c0 < N_CLS) out[(size_t)bag * N_CLS + c0] = a0 + bias[c0];
        if (c1 < N_CLS) out[(size_t)bag * N_CLS + c1] = a1 + bias[c1];
    }
}

// ---------------------------------------------------------------------------
extern "C" void kernel_launch(void* const* d_in, const int* in_sizes, int n_in,
                              void* d_out, int out_size, void* d_ws, size_t ws_size,
                              hipStream_t stream)
{
    const float* x     = (const float*)d_in[0];
    const float* rel_w = (const float*)d_in[1];
    const float* att_w = (const float*)d_in[2];
    const float* bias  = (const float*)d_in[3];
    const int*   query = (const int*)d_in[4];
    const int*   scope = (const int*)d_in[5];
    float*       out   = (float*)d_out;

    const int n_sent = in_sizes[0] / DIM;      // 262144
    const int n_bags = in_sizes[5] - 1;        // 8192

    // workspace layout
    unsigned short* wbp   = (unsigned short*)d_ws;             // 45056
    unsigned short* awb   = wbp + NCHUNK * 4 * 512;            // 45056
    float*          logit = (float*)(awb + 64 * KPAD);         // n_sent
    unsigned short* y     = (unsigned short*)(logit + n_sent); // n_sent*YLD

    prep_kernel<<<(NCHUNK * 4 * 512 + 64 * KPAD + 255) / 256, 256, 0, stream>>>(
        rel_w, att_w, wbp, awb);

    score_kernel<<<GRID_SCORE, 256, 0, stream>>>(x, wbp, awb, query, y, logit);

    bag_kernel<<<(n_bags + 3) / 4, 256, 0, stream>>>(y, logit, bias, scope, out, n_bags);
}

// Round 5
// 209.651 us; speedup vs baseline: 3.0669x; 1.1116x over previous
//
#include <hip/hip_runtime.h>
#include <hip/hip_bf16.h>
#include <cfloat>

#define DIM 690
#define KPAD 704          // aw row stride (22 chunks of 32)
#define NCHUNK 22
#define N_CLS 53
#define YLD 64            // y row stride in shorts (128 B rows)
#define BM 16             // rows per slab
#define LDS_LD 696        // LDS row stride in shorts: 1392 B = 16B-aligned, 2-way-free b128
#define GRID_SCORE 768    // 3 blocks/CU x 256 CU
#define NSLAB 16384       // 262144 / BM

typedef short bf16x8 __attribute__((ext_vector_type(8)));
typedef float f32x4  __attribute__((ext_vector_type(4)));

static __device__ __forceinline__ float bf2f(unsigned short u) {
    union { unsigned int i; float f; } v; v.i = ((unsigned int)u) << 16; return v.f;
}
static __device__ __forceinline__ unsigned short f2bf(float f) {
    __hip_bfloat16 h = __float2bfloat16(f);
    return *reinterpret_cast<unsigned short*>(&h);
}

// ---------------------------------------------------------------------------
// P0: pack
//  wbp — fragment-ordered B: wbp[((kk*4+kg)*64 + c)*8 + j] = bf16(rel_w[c][k]),
//        k = kk*32 + kg*8 + j, zero-padded (c>=53 or k>=690)
//  awb — row-major bf16(att*rel) [64][704], zero-padded
// ---------------------------------------------------------------------------
__global__ __launch_bounds__(256) void prep_kernel(
    const float* __restrict__ rel_w, const float* __restrict__ att_w,
    unsigned short* __restrict__ wbp, unsigned short* __restrict__ awb)
{
    int idx = blockIdx.x * blockDim.x + threadIdx.x;
    const int NW = NCHUNK * 4 * 512;   // 45056
    const int NA = 64 * KPAD;          // 45056
    if (idx < NW) {
        int kkg = idx >> 9;            // kk*4+kg
        int rem = idx & 511;
        int c = rem >> 3, j = rem & 7;
        int k = (kkg >> 2) * 32 + (kkg & 3) * 8 + j;
        float v = (c < N_CLS && k < DIM) ? rel_w[c * DIM + k] : 0.f;
        wbp[idx] = f2bf(v);
    } else if (idx < NW + NA) {
        int i2 = idx - NW;
        int rr = i2 / KPAD, k = i2 - rr * KPAD;
        float v = 0.f;
        if (rr < N_CLS && k < DIM) v = att_w[rr * DIM + k] * rel_w[rr * DIM + k];
        awb[i2] = f2bf(v);
    }
}

// ---------------------------------------------------------------------------
// K1: fused score GEMM + attention logit. Persistent blocks, BM=16 slabs,
// double-buffered LDS, ONE barrier per slab, T14 load-early/write-late.
// LDS_LD=696: b128 frag reads are 16B-aligned and uniformly 2-way (free).
// Wave w: cols 16w..16w+15 (1 MFMA/chunk); logit partial on chunks [6w,6w+6).
// lgp is parity-double-buffered; logit(t-1) finalized during iteration t.
// ---------------------------------------------------------------------------
__global__ __launch_bounds__(256, 3) void score_kernel(
    const float* __restrict__ x,
    const unsigned short* __restrict__ wbp,
    const unsigned short* __restrict__ awb,
    const int* __restrict__ query,
    unsigned short* __restrict__ y,
    float* __restrict__ logit)
{
    __shared__ unsigned short xs[2][BM * LDS_LD + 8];
    __shared__ float lgp[2][4][16];

    const int t = threadIdx.x;
    const int lane = t & 63;
    const int wv = t >> 6;
    const int r = lane & 15, kg = lane >> 4;
    const int srow = t >> 4, sub = t & 15;   // stage: 16 threads per row

    // zero per-row pads (cols 690..695) and the 8-short tile tail, both bufs,
    // so kk=21 fragment tails read exact zeros (never NaN-pattern garbage).
    if (t < 104) {
        int b = t >= 52; int j = b ? t - 52 : t;
        unsigned int off;  // u32 index within buffer
        if (j < 48) { int row = j / 3, c = j % 3; off = (unsigned)(row * LDS_LD + 690) / 2 + c; }
        else        { off = (unsigned)(BM * LDS_LD) / 2 + (j - 48); }
        reinterpret_cast<unsigned int*>(xs[b])[off] = 0u;
    }

    float2 sreg[NCHUNK];

    auto load_slab = [&](int s) {
        const float* xrow = x + ((size_t)s * BM + srow) * DIM;
        #pragma unroll
        for (int i = 0; i < NCHUNK; ++i) {
            int col = i * 32 + sub * 2;
            if (col <= 688)
                sreg[i] = *reinterpret_cast<const float2*>(xrow + col);
        }
    };
    auto write_slab = [&](int b) {
        unsigned short* base = xs[b] + srow * LDS_LD;
        #pragma unroll
        for (int i = 0; i < NCHUNK; ++i) {
            int col = i * 32 + sub * 2;
            if (col <= 688) {
                unsigned int p = (unsigned int)f2bf(sreg[i].x)
                               | ((unsigned int)f2bf(sreg[i].y) << 16);
                *reinterpret_cast<unsigned int*>(base + col) = p;
            }
        }
    };

    int slab = blockIdx.x;
    load_slab(slab);
    write_slab(0);
    __syncthreads();

    int buf = 0, it = 0, prev = -1;
    const int lo = wv * 6;
    const int hi = (lo + 6 < NCHUNK) ? lo + 6 : NCHUNK;

    while (true) {
        const int next = slab + GRID_SCORE;
        const bool has_next = next < NSLAB;

        if (has_next) load_slab(next);     // issue-early (T14)

        // ---- compute current slab ----
        {
            const int rowBase = slab * BM;
            const unsigned short* awrow = awb + (size_t)query[rowBase + r] * KPAD;
            const unsigned short* xbase = xs[buf] + r * LDS_LD;
            f32x4 acc = {0.f, 0.f, 0.f, 0.f};
            float lg = 0.f;
            #pragma unroll
            for (int kk = 0; kk < NCHUNK; ++kk) {
                bf16x8 af = *reinterpret_cast<const bf16x8*>(xbase + kk * 32 + kg * 8);
                bf16x8 bw = *reinterpret_cast<const bf16x8*>(
                    wbp + (size_t)(((kk * 4 + kg) * 64 + wv * 16 + r) * 8));
                if (kk >= lo && kk < hi) {   // wave-uniform
                    bf16x8 awf = *reinterpret_cast<const bf16x8*>(awrow + kk * 32 + kg * 8);
                    #pragma unroll
                    for (int j = 0; j < 8; ++j)
                        lg += bf2f((unsigned short)af[j]) * bf2f((unsigned short)awf[j]);
                }
                acc = __builtin_amdgcn_mfma_f32_16x16x32_bf16(af, bw, acc, 0, 0, 0);
            }
            lg += __shfl_xor(lg, 16);
            lg += __shfl_xor(lg, 32);
            if (lane < 16) lgp[it & 1][wv][lane] = lg;

            #pragma unroll
            for (int reg = 0; reg < 4; ++reg)
                y[(size_t)(rowBase + kg * 4 + reg) * YLD + wv * 16 + r] = f2bf(acc[reg]);
        }

        // finalize previous slab's logit (lgp parity it-1; complete since last barrier)
        if (prev >= 0 && t < 16) {
            int p = (it - 1) & 1;
            logit[prev * BM + t] = lgp[p][0][t] + lgp[p][1][t] + lgp[p][2][t] + lgp[p][3][t];
        }

        if (has_next) write_slab(buf ^ 1); // write-late (vmcnt drains here, after compute)
        __syncthreads();                   // single barrier per slab

        if (!has_next) break;
        prev = slab; slab = next; buf ^= 1; ++it;
    }
    // final slab's logit (its lgp sealed by the loop's last barrier)
    if (t < 16) {
        int p = it & 1;
        logit[slab * BM + t] = lgp[p][0][t] + lgp[p][1][t] + lgp[p][2][t] + lgp[p][3][t];
    }
}

// ---------------------------------------------------------------------------
// K2: one block (4 waves) per bag. Each wave: full softmax stats (cheap,
// L2-hot logit), then weighted y-sum over its row pairs; LDS cross-wave
// reduce. Lanes: cp=lane&31 -> cols 2cp,2cp+1 (u32 = 2 bf16); rpar = row
// parity. Per instruction: 2 rows x 128 B contiguous.
// ---------------------------------------------------------------------------
__global__ __launch_bounds__(256) void bag_kernel(
    const unsigned short* __restrict__ y,
    const float* __restrict__ logit,
    const float* __restrict__ bias,
    const int* __restrict__ scope,
    float* __restrict__ out)
{
    const int bag = blockIdx.x;
    const int t = threadIdx.x, lane = t & 63, wv = t >> 6;
    const int s = scope[bag], e = scope[bag + 1];

    __shared__ float red[4][64];

    float m = -FLT_MAX;
    for (int i = s + lane; i < e; i += 64) m = fmaxf(m, logit[i]);
    #pragma unroll
    for (int off = 32; off > 0; off >>= 1) m = fmaxf(m, __shfl_xor(m, off));

    float sum = 0.f;
    for (int i = s + lane; i < e; i += 64) sum += __expf(logit[i] - m);
    #pragma unroll
    for (int off = 32; off > 0; off >>= 1) sum += __shfl_xor(sum, off);
    const float inv = 1.f / sum;

    const int cp = lane & 31;
    const int rpar = lane >> 5;
    const unsigned int* yu = reinterpret_cast<const unsigned int*>(y);

    float a0 = 0.f, a1 = 0.f;
    for (int base = s + wv * 2; base < e; base += 8) {
        int row = base + rpar;
        if (row < e) {
            float w = __expf(logit[row] - m) * inv;
            unsigned int v = yu[(size_t)row * (YLD / 2) + cp];
            union { unsigned int i; float f; } lof, hif;
            lof.i = v << 16;
            hif.i = v & 0xFFFF0000u;
            a0 += w * lof.f;
            a1 += w * hif.f;
        }
    }
    a0 += __shfl_xor(a0, 32);
    a1 += __shfl_xor(a1, 32);
    if (lane < 32) { red[wv][lane] = a0; red[wv][32 + lane] = a1; }
    __syncthreads();
    if (t < 64) {
        float v = red[0][t] + red[1][t] + red[2][t] + red[3][t];
        int c = (t < 32) ? 2 * t : 2 * (t - 32) + 1;
        if (c < N_CLS) out[(size_t)bag * N_CLS + c] = v + bias[c];
    }
}

// ---------------------------------------------------------------------------
extern "C" void kernel_launch(void* const* d_in, const int* in_sizes, int n_in,
                              void* d_out, int out_size, void* d_ws, size_t ws_size,
                              hipStream_t stream)
{
    const float* x     = (const float*)d_in[0];
    const float* rel_w = (const float*)d_in[1];
    const float* att_w = (const float*)d_in[2];
    const float* bias  = (const float*)d_in[3];
    const int*   query = (const int*)d_in[4];
    const int*   scope = (const int*)d_in[5];
    float*       out   = (float*)d_out;

    const int n_sent = in_sizes[0] / DIM;      // 262144
    const int n_bags = in_sizes[5] - 1;        // 8192

    // workspace layout
    unsigned short* wbp   = (unsigned short*)d_ws;             // 45056
    unsigned short* awb   = wbp + NCHUNK * 4 * 512;            // 45056
    float*          logit = (float*)(awb + 64 * KPAD);         // n_sent
    unsigned short* y     = (unsigned short*)(logit + n_sent); // n_sent*YLD

    prep_kernel<<<(NCHUNK * 4 * 512 + 64 * KPAD + 255) / 256, 256, 0, stream>>>(
        rel_w, att_w, wbp, awb);

    score_kernel<<<GRID_SCORE, 256, 0, stream>>>(x, wbp, awb, query, y, logit);

    bag_kernel<<<n_bags, 256, 0, stream>>>(y, logit, bias, scope, out);
}